// Round 13
// baseline (770.956 us; speedup 1.0000x reference)
//
#include <hip/hip_runtime.h>
#include <hip/hip_bf16.h>
#include <math.h>

typedef __hip_bfloat16 bf16;
typedef short short8 __attribute__((ext_vector_type(8)));   // bf16x8 MFMA frag (4 VGPRs)
typedef float f32x4 __attribute__((ext_vector_type(4)));    // MFMA accumulator

static __device__ __forceinline__ float b2f(bf16 x) { return __bfloat162float(x); }
static __device__ __forceinline__ bf16  f2b(float x) { return __float2bfloat16(x); }
static __device__ __forceinline__ short f2bs(float x) { bf16 t = f2b(x); return *reinterpret_cast<short*>(&t); }

// Polymorphic input load: isb=true -> bf16 storage, else f32 storage.
static __device__ __forceinline__ float ldin(const void* p, size_t i, bool isb) {
    return isb ? b2f(((const bf16*)p)[i]) : ((const float*)p)[i];
}

// ---------------------------------------------------------------- dtype detect
__global__ void detect_kernel(const unsigned int* __restrict__ x, float* __restrict__ flagp) {
    __shared__ int sh[64];
    int insane = 0;
    for (int i = threadIdx.x; i < 1024; i += 64) {
        unsigned int lo = (x[i] & 0xFFFFu) << 16;
        float v = __uint_as_float(lo);
        if (!(fabsf(v) <= 1e6f)) insane++;
    }
    sh[threadIdx.x] = insane;
    __syncthreads();
    if (threadIdx.x == 0) {
        int t = 0;
        for (int i = 0; i < 64; ++i) t += sh[i];
        *flagp = (t < 16) ? 1.f : 0.f;            // 1 => inputs are bf16
    }
}

// ---------------------------------------------------------------- diagnostic fill
__global__ void diag_fill(unsigned int* __restrict__ out, int nwords, float val) {
    int i = blockIdx.x * blockDim.x + threadIdx.x;
    if (i < nwords) {
        unsigned short h = (unsigned short)(__float_as_uint(val) >> 16);
        out[i] = ((unsigned int)h << 16) | h;
    }
}

// ---------------------------------------------------------------- weight pack: [co][ci][tap] -> [tap][co][ci] bf16
__global__ void wpack_kernel(const void* __restrict__ wt, const float* __restrict__ flg,
                             bf16* __restrict__ dst, int Cout, int Cin) {
    bool isb = (*flg != 0.f);
    int n = Cout * Cin * 9;
    int idx = blockIdx.x * blockDim.x + threadIdx.x;
    if (idx >= n) return;
    int ci = idx % Cin;
    int co = (idx / Cin) % Cout;
    int tap = idx / (Cin * Cout);
    dst[idx] = f2b(ldin(wt, ((size_t)co * Cin + ci) * 9 + tap, isb));
}

// ---------------------------------------------------------------- flat convert to bf16 (caun kw pack)
__global__ void b2bpack(const void* __restrict__ src, const float* __restrict__ flg,
                        bf16* __restrict__ dst, int n) {
    bool isb = (*flg != 0.f);
    int i = blockIdx.x * blockDim.x + threadIdx.x;
    if (i < n) dst[i] = f2b(ldin(src, i, isb));
}

// ---------------------------------------------------------------- NCHW ext -> channels-last bf16 (LDS tile transpose)
__global__ void nchw2cl(const void* __restrict__ in, const float* __restrict__ flg,
                        bf16* __restrict__ out, int C, int HW) {
    __shared__ bf16 t[32][72];
    bool isb = (*flg != 0.f);
    int npx = HW >> 6, nc = C >> 5;
    int blk = blockIdx.x;
    int px0 = (blk % npx) << 6;
    int c0  = ((blk / npx) % nc) << 5;
    int b   = blk / (npx * nc);
    for (int i = threadIdx.x; i < 2048; i += 256) {
        int px = i & 63, c = i >> 6;
        t[c][px] = f2b(ldin(in, ((size_t)(b * C + c0 + c)) * HW + px0 + px, isb));
    }
    __syncthreads();
    for (int i = threadIdx.x; i < 2048; i += 256) {
        int c = i & 31, px = i >> 5;
        out[((size_t)b * HW + px0 + px) * C + c0 + c] = t[c][px];
    }
}

// ---------------------------------------------------------------- 2x2 mean pool: NCHW ext -> channels-last bf16 ws
__global__ void pool2_cl(const void* __restrict__ in, const float* __restrict__ flg,
                         bf16* __restrict__ out, int B, int C, int H2, int W2) {
    bool isb = (*flg != 0.f);
    int idx = blockIdx.x * blockDim.x + threadIdx.x;
    int total = B * H2 * W2 * C;
    if (idx >= total) return;
    int c = idx % C;
    int pix = idx / C;
    int w = pix % W2;
    int h = (pix / W2) % H2;
    int b = pix / (W2 * H2);
    int H = H2 * 2, W = W2 * 2;
    size_t base = ((size_t)(b * C + c)) * H * W;
    float s = ldin(in, base + (size_t)(2*h)*W + 2*w, isb)   + ldin(in, base + (size_t)(2*h)*W + 2*w + 1, isb)
            + ldin(in, base + (size_t)(2*h+1)*W + 2*w, isb) + ldin(in, base + (size_t)(2*h+1)*W + 2*w + 1, isb);
    out[idx] = f2b(0.25f * s);
}

// ---------------------------------------------------------------- MFMA conv3x3, channels-last, no LDS (kw-outer)
template<int RT>
__global__ __launch_bounds__(256) void conv3x3_cl(
        const void* __restrict__ in1, int C1, int ext1,
        const bf16* __restrict__ in2, int C2,
        const bf16* __restrict__ wp,
        const void* __restrict__ bias,
        const void* __restrict__ alpha,
        const float* __restrict__ flg,
        bf16* __restrict__ out,
        int H, int W, int Cout, int act) {
    const bool isb = (*flg != 0.f);
    const int Cin = C1 + C2;
    const int lane = threadIdx.x & 63;
    const int wave = threadIdx.x >> 6;
    const int quad = lane >> 4, l16 = lane & 15;
    const int cot = Cout >> 4;
    const int b = blockIdx.z / cot;
    const int co_base = (blockIdx.z % cot) << 4;
    const int r0 = (blockIdx.y * 4 + wave) * RT;
    const int c0 = blockIdx.x << 4;
    const int cog = co_base + l16;

    float bv = ldin(bias, cog, isb);
    f32x4 acc[RT];
    #pragma unroll
    for (int t = 0; t < RT; ++t) acc[t] = {bv, bv, bv, bv};

    for (int ci0 = 0; ci0 < Cin; ci0 += 32) {
        const bool from1 = (ci0 < C1);
        #pragma unroll
        for (int kw = 0; kw < 3; ++kw) {
            const int iw = c0 + l16 + kw - 1;
            const bool okc = (iw >= 0) && (iw < W);
            short8 F[RT + 2];
            #pragma unroll
            for (int j = 0; j < RT + 2; ++j) {
                const int ih = r0 + j - 1;
                const bool ok = okc && (ih >= 0) && (ih < H);
                F[j] = short8{0, 0, 0, 0, 0, 0, 0, 0};
                if (from1) {
                    if (ext1) {
                        if (ok) {
                            size_t base = ((size_t)(b * C1 + ci0 + quad * 8)) * H * W
                                        + (size_t)ih * W + iw;
                            #pragma unroll
                            for (int jj = 0; jj < 8; ++jj)
                                F[j][jj] = f2bs(ldin(in1, base + (size_t)jj * H * W, isb));
                        }
                    } else {
                        if (ok)
                            F[j] = *(const short8*)&((const bf16*)in1)[
                                (((size_t)(b * H) + ih) * W + iw) * C1 + ci0 + quad * 8];
                    }
                } else {
                    if (ok)
                        F[j] = *(const short8*)&in2[(((size_t)(b * H) + ih) * W + iw) * C2
                                                     + (ci0 - C1) + quad * 8];
                }
            }
            #pragma unroll
            for (int kh = 0; kh < 3; ++kh) {
                short8 bfrag = *(const short8*)&wp[((size_t)(kh * 3 + kw) * Cout + cog) * Cin
                                                   + ci0 + quad * 8];
                #pragma unroll
                for (int t = 0; t < RT; ++t)
                    acc[t] = __builtin_amdgcn_mfma_f32_16x16x32_bf16(F[t + kh], bfrag, acc[t], 0, 0, 0);
            }
        }
    }

    float a = (act == 2) ? ldin(alpha, cog, isb) : 0.f;
    #pragma unroll
    for (int t = 0; t < RT; ++t) {
        #pragma unroll
        for (int reg = 0; reg < 4; ++reg) {
            float v = acc[t][reg];
            if (act == 1) v = fmaxf(v, 0.f);
            else if (act == 2) v = (v >= 0.f) ? v : a * v;
            out[(((size_t)(b * H) + r0 + t) * W + c0 + (quad << 2) + reg) * Cout + cog] = f2b(v);
        }
    }
}

// ---------------------------------------------------------------- CAUN v3: block = (8x8 input tile, b, 64-ch chunk)
// All 64 channels of the block's output positions owned in-block -> contiguous
// c-major writes (kills the 12x write amplification of per-(b,c) scatter).
// Per c: 3 j-tile MFMA (A = packed kw, direct global 16B; B = f frags hoisted),
// wave-private LDS transpose (no barrier), epilogue softmax+blend from LDS-staged
// neighbors, store to out_s[c][16x16]; final cooperative coalesced write.
// kwp: bf16 [C*36][K]. K in {16,32,64}. H==W (square). CC=64 divides C.
#define CAUN_CC 64
__global__ __launch_bounds__(256) void caun_v3(
        const bf16* __restrict__ f,
        const void* __restrict__ xlow, int xext,
        const bf16* __restrict__ kwp,
        const void* __restrict__ kb,
        const float* __restrict__ flg,
        bf16* __restrict__ out,
        int C, int K, int H, int W) {
    __shared__ float lg_s[4][48 * 17];       // per-wave D transpose
    __shared__ float kb_s[36 * 66];          // bias, [j][c] padded
    __shared__ bf16  neigh_s[100 * 66];      // 10x10 halo x CC, [cell][c] padded
    __shared__ bf16  out_s[CAUN_CC * 258];   // [c][16x16 px] padded

    const bool isb = (*flg != 0.f);
    const int tw = W >> 3;
    const int h0 = (blockIdx.x / tw) << 3;
    const int w0 = (blockIdx.x % tw) << 3;
    const int b  = blockIdx.y;
    const int c0 = blockIdx.z * CAUN_CC;
    const int tid = threadIdx.x, wave = tid >> 6, lane = tid & 63;
    const int quad = lane >> 4, l16 = lane & 15;

    // ---- stage clamped neighbor halo (c-contiguous loads)
    for (int i = tid; i < 100 * CAUN_CC; i += 256) {
        int c = i & 63, cell = i >> 6;
        int r = cell / 10, q = cell % 10;
        int ih = min(max(h0 + r - 1, 0), H - 1);
        int iw = min(max(w0 + q - 1, 0), W - 1);
        float v = xext
            ? ldin(xlow, ((size_t)(b * C + c0 + c)) * H * W + (size_t)ih * W + iw, isb)
            : b2f(((const bf16*)xlow)[(((size_t)(b * H) + ih) * W + iw) * C + c0 + c]);
        neigh_s[cell * 66 + c] = f2b(v);
    }
    // ---- stage bias chunk
    for (int i = tid; i < 36 * CAUN_CC; i += 256) {
        int c = i & 63, j = i >> 6;
        kb_s[j * 66 + c] = ldin(kb, (size_t)(c0 + c) * 36 + j, isb);
    }

    // ---- hoist B-frags (f) for this wave's 16 px (2 input rows x 8 cols)
    const int hl = (wave << 1) + (l16 >> 3);
    const int wl = l16 & 7;
    const size_t fpx = ((size_t)b * H * W + (size_t)(h0 + hl) * W + (w0 + wl)) * K;
    const int nkc = ((K + 31) & ~31) >> 5;          // 1 or 2
    const short8 z8 = {0, 0, 0, 0, 0, 0, 0, 0};
    short8 Bf[2];
    {
        int kq0 = quad * 8;
        Bf[0] = (kq0 < K) ? *(const short8*)&f[fpx + kq0] : z8;
        Bf[1] = (nkc > 1) ? *(const short8*)&f[fpx + 32 + quad * 8] : z8;
    }
    __syncthreads();

    // epilogue lane mapping: px16 = lane>>2 (== MFMA l16/D-col), g = lane&3
    const int epx = lane >> 2, eg = lane & 3;
    const int hl_e = (wave << 1) + (epx >> 3);
    const int wl_e = epx & 7;
    float* ls = &lg_s[wave][0];

    for (int c = 0; c < CAUN_CC; ++c) {
        const size_t crow = (size_t)(c0 + c) * 36;
        f32x4 a0 = {0,0,0,0}, a1 = {0,0,0,0}, a2 = {0,0,0,0};
        #pragma unroll
        for (int ch = 0; ch < 2; ++ch) {
            if (ch >= nkc) break;
            int kq = ch * 32 + quad * 8;
            bool kok = kq < K;
            short8 f0 = kok ? *(const short8*)&kwp[(crow + l16) * K + kq] : z8;
            short8 f1 = kok ? *(const short8*)&kwp[(crow + 16 + l16) * K + kq] : z8;
            short8 f2 = (kok && l16 < 4) ? *(const short8*)&kwp[(crow + 32 + l16) * K + kq] : z8;
            a0 = __builtin_amdgcn_mfma_f32_16x16x32_bf16(f0, Bf[ch], a0, 0, 0, 0);
            a1 = __builtin_amdgcn_mfma_f32_16x16x32_bf16(f1, Bf[ch], a1, 0, 0, 0);
            a2 = __builtin_amdgcn_mfma_f32_16x16x32_bf16(f2, Bf[ch], a2, 0, 0, 0);
        }
        // wave-private transpose (no barrier needed)
        #pragma unroll
        for (int reg = 0; reg < 4; ++reg) {
            int jr = (quad << 2) + reg;
            ls[jr * 17 + l16]        = a0[reg];
            ls[(16 + jr) * 17 + l16] = a1[reg];
            ls[(32 + jr) * 17 + l16] = a2[reg];
        }
        // epilogue: lane = (px16, g)
        float lg[9], nv[9];
        #pragma unroll
        for (int n = 0; n < 9; ++n) {
            int j = n * 4 + eg;
            lg[n] = ls[j * 17 + epx] + kb_s[j * 66 + c];
            int cell = (hl_e + n / 3) * 10 + (wl_e + n % 3);
            nv[n] = b2f(neigh_s[cell * 66 + c]);
        }
        float mx = -1e30f;
        #pragma unroll
        for (int n = 0; n < 9; ++n) mx = fmaxf(mx, lg[n]);
        float se = 0.f, accv = 0.f;
        #pragma unroll
        for (int n = 0; n < 9; ++n) {
            float e = expf(lg[n] - mx);
            se += e;
            accv = fmaf(e, nv[n], accv);
        }
        int row_l = (wl_e << 1) + (eg & 1);     // 2w+v
        int col_l = (hl_e << 1) + (eg >> 1);    // 2h+u
        out_s[c * 258 + (row_l << 4) + col_l] = f2b(accv / se);
    }

    __syncthreads();
    // ---- coalesced write-out: consecutive lanes -> consecutive c
    const size_t obase = (size_t)b * 4 * H * W;
    for (int i = tid; i < 256 * CAUN_CC; i += 256) {
        int c = i & 63, pxl = i >> 6;
        int row_l = pxl >> 4, col_l = pxl & 15;
        size_t P = obase + (size_t)(2 * w0 + row_l) * (2 * W) + (2 * h0 + col_l);
        out[P * C + c0 + c] = out_s[c * 258 + pxl];
    }
}

// ---------------------------------------------------------------- memory bank: row-l2norm of mem
__global__ void memnorm_kernel(const void* __restrict__ mem, const float* __restrict__ flg,
                               float* __restrict__ mn) {
    bool isb = (*flg != 0.f);
    int s = threadIdx.x;
    float v[32];
    float ss = 0.f;
    #pragma unroll
    for (int c = 0; c < 32; ++c) { v[c] = ldin(mem, s * 32 + c, isb); ss += v[c] * v[c]; }
    float inv = 1.f / fmaxf(sqrtf(ss), 1e-12f);
    #pragma unroll
    for (int c = 0; c < 32; ++c) mn[s * 32 + c] = v[c] * inv;
}

// ---------------------------------------------------------------- memory fusion (in place, channels-last bf16 ws)
__global__ __launch_bounds__(256, 2) void memfuse_kernel(
        bf16* __restrict__ x, const float* __restrict__ mn) {
    __shared__ float mns[64 * 32];
    for (int i = threadIdx.x; i < 64 * 32; i += blockDim.x) mns[i] = mn[i];
    __syncthreads();
    int idx = blockIdx.x * blockDim.x + threadIdx.x;
    bf16* xp = x + (size_t)idx * 32;

    float feat[32];
    float ss = 0.f;
    #pragma unroll
    for (int c = 0; c < 32; ++c) { feat[c] = b2f(xp[c]); ss += feat[c] * feat[c]; }
    float inv = 1.f / fmaxf(sqrtf(ss), 1e-12f);

    float se = 0.f;
    float racc[32];
    #pragma unroll
    for (int c = 0; c < 32; ++c) racc[c] = 0.f;

    for (int s = 0; s < 64; ++s) {
        const float* mr = mns + s * 32;
        float dot = 0.f;
        #pragma unroll
        for (int c = 0; c < 32; ++c) dot = fmaf(feat[c], mr[c], dot);
        float e = expf(dot * inv);
        se += e;
        #pragma unroll
        for (int c = 0; c < 32; ++c) racc[c] = fmaf(e, mr[c], racc[c]);
    }
    float rse = 1.f / se;
    #pragma unroll
    for (int c = 0; c < 32; ++c)
        xp[c] = f2b(feat[c] + racc[c] * rse);
}

// ---------------------------------------------------------------- final 1x1 conv 32 -> 2 (x channels-last)
__global__ void final1x1_kernel(const bf16* __restrict__ x,
                                const void* __restrict__ fw, const void* __restrict__ fb,
                                const float* __restrict__ flg,
                                void* __restrict__ out, int HW) {
    bool isb = (*flg != 0.f);
    int idx = blockIdx.x * blockDim.x + threadIdx.x;
    int b = idx / HW, p = idx % HW;
    const bf16* xp = x + (size_t)idx * 32;
    float a0 = ldin(fb, 0, isb), a1 = ldin(fb, 1, isb);
    #pragma unroll
    for (int c = 0; c < 32; ++c) {
        float v = b2f(xp[c]);
        a0 = fmaf(v, ldin(fw, c, isb), a0);
        a1 = fmaf(v, ldin(fw, 32 + c, isb), a1);
    }
    size_t i0 = (size_t)b * 2 * HW + p;
    size_t i1 = i0 + HW;
    if (isb) { ((bf16*)out)[i0] = f2b(a0); ((bf16*)out)[i1] = f2b(a1); }
    else     { ((float*)out)[i0] = a0;     ((float*)out)[i1] = a1; }
}

// ================================================================ host
extern "C" void kernel_launch(void* const* d_in, const int* in_sizes, int n_in,
                              void* d_out, int out_size, void* d_ws, size_t ws_size,
                              hipStream_t stream) {
    const void* x0_0 = d_in[0];
    const void* x1_0 = d_in[1];
    const void* x2_0 = d_in[2];
    const void* x3_0 = d_in[3];
    const void* c3_w1 = d_in[4];  const void* c3_b1 = d_in[5];  const void* c3_a1 = d_in[6];
    const void* c3_w2 = d_in[7];  const void* c3_b2 = d_in[8];  const void* c3_a2 = d_in[9];
    const void* c3_kw = d_in[10]; const void* c3_kb = d_in[11];
    const void* c2_w1 = d_in[12]; const void* c2_b1 = d_in[13]; const void* c2_a1 = d_in[14];
    const void* c2_w2 = d_in[15]; const void* c2_b2 = d_in[16]; const void* c2_a2 = d_in[17];
    const void* c2_kw = d_in[18]; const void* c2_kb = d_in[19];
    const void* c1_w1 = d_in[20]; const void* c1_b1 = d_in[21]; const void* c1_a1 = d_in[22];
    const void* c1_w2 = d_in[23]; const void* c1_b2 = d_in[24]; const void* c1_a2 = d_in[25];
    const void* c1_kw = d_in[26]; const void* c1_kb = d_in[27];
    const void* b21_w1 = d_in[28]; const void* b21_b1 = d_in[29];
    const void* b21_w2 = d_in[30]; const void* b21_b2 = d_in[31];
    const void* b12_w1 = d_in[32]; const void* b12_b1 = d_in[33];
    const void* b12_w2 = d_in[34]; const void* b12_b2 = d_in[35];
    const void* b03_w1 = d_in[36]; const void* b03_b1 = d_in[37];
    const void* b03_w2 = d_in[38]; const void* b03_b2 = d_in[39];
    const void* fin_w = d_in[40];  const void* fin_b = d_in[41];
    const void* memw  = d_in[42];
    (void)in_sizes; (void)n_in;

    const int TB = 256;
    auto blocks = [](int n) { return (n + 255) / 256; };

    const size_t NEED = 25165824 + 65536;
    if (ws_size < NEED) {
        diag_fill<<<blocks(out_size / 2), TB, 0, stream>>>(
            (unsigned int*)d_out, out_size / 2, (float)ws_size);
        return;
    }
    const size_t NEED_X0 = 25165824 + 8388608 + 65536 + 256;
    const bool have_x0cl = (ws_size >= NEED_X0);

    size_t tail = (ws_size - 65536) & ~(size_t)255;
    bf16*  wtail = (bf16*)((char*)d_ws + tail);
    float* mn    = (float*)((char*)d_ws + tail + 55296);
    float* flg   = (float*)((char*)d_ws + tail + 63488);

    // 24 MiB arena (12,582,912 bf16 elems), channels-last, verified live ranges.
    bf16* A = (bf16*)d_ws;
    bf16* x3up  = A + 0;         // [2,64,64,256]
    bf16* ctx3p = A + 2097152;   // [2,32,32,128]
    bf16* f3a   = A + 2359296;   // [2,32,32,128]
    bf16* f3b   = A + 2621440;   // [2,32,32,64]
    bf16* kw3p  = A + 3000000;   // 589,824 elems (free during caun3)
    bf16* t2a   = A + 2097152;   // [2,64,64,128]
    bf16* x2cl  = A + 3145728;   // [2,64,64,128]
    bf16* x2_1  = A + 0;         // [2,64,64,128]
    bf16* ctx2  = A + 1048576;   // [2,64,64,64]
    bf16* f2a   = A + 1572864;   // [2,64,64,64]
    bf16* f2b   = A + 2097152;   // [2,64,64,32]
    bf16* x2up  = A + 2359296;   // [2,128,128,128]
    bf16* t1a   = A + 0;         // [2,128,128,64]
    bf16* x1cl  = A + 6995968;   // [2,128,128,64]
    bf16* x1_2  = A + 10485760;  // [2,128,128,64]
    bf16* ctx1  = A + 4194304;   // [2,128,128,32]
    bf16* f1a   = A + 5242880;   // [2,128,128,32]
    bf16* f1b   = A + 9437184;   // [2,128,128,16]
    bf16* kw1p  = A + 8388608;   // 36,864 elems (free gap during caun1)
    bf16* x1up  = A + 0;         // [2,256,256,64]
    bf16* t0a   = A + 8388608;   // [2,256,256,32]
    bf16* x0_3  = A + 0;         // [2,256,256,32]
    bf16* wslot = A + 6553600;   // conv weight packs + caun2 kw pack
    bf16* x0cl  = A + 12582912;  // [2,256,256,32] (only if have_x0cl)

    detect_kernel<<<1, 64, 0, stream>>>((const unsigned int*)x0_0, flg);

    auto wpk = [&](const void* w, bf16* dst, int Cout, int Cin) {
        wpack_kernel<<<blocks(Cout * Cin * 9), TB, 0, stream>>>(w, flg, dst, Cout, Cin);
    };
    auto cg = [](int H, int W, int Cout, int RT) {
        return dim3(W >> 4, H / (4 * RT), 2 * (Cout >> 4));
    };

    if (have_x0cl)
        nchw2cl<<<2 * 1 * 1024, TB, 0, stream>>>(x0_0, flg, x0cl, 32, 65536);

    // ---- caun3: ctx = pool(x2_0) -> [2,32,32,128] cl
    pool2_cl<<<blocks(262144), TB, 0, stream>>>(x2_0, flg, ctx3p, 2, 128, 32, 32);
    wpk(c3_w1, wslot, 128, 128);
    conv3x3_cl<1><<<cg(32, 32, 128, 1), TB, 0, stream>>>(
        nullptr, 0, 0, ctx3p, 128, wslot, c3_b1, c3_a1, flg, f3a, 32, 32, 128, 2);
    wpk(c3_w2, wslot, 64, 128);
    conv3x3_cl<1><<<cg(32, 32, 64, 1), TB, 0, stream>>>(
        nullptr, 0, 0, f3a, 128, wslot, c3_b2, c3_a2, flg, f3b, 32, 32, 64, 2);
    b2bpack<<<blocks(256 * 36 * 64), TB, 0, stream>>>(c3_kw, flg, kw3p, 256 * 36 * 64);
    caun_v3<<<dim3(16, 2, 4), TB, 0, stream>>>(
        f3b, x3_0, 1, kw3p, c3_kb, flg, x3up, 256, 64, 32, 32);

    // ---- block21: cat(x2_0 -> cl [128], x3up cl[256]) -> 128 -> 128 @64x64
    nchw2cl<<<2 * 4 * 64, TB, 0, stream>>>(x2_0, flg, x2cl, 128, 4096);
    wpk(b21_w1, wslot, 128, 384);
    conv3x3_cl<2><<<cg(64, 64, 128, 2), TB, 0, stream>>>(
        x2cl, 128, 0, x3up, 256, wslot, b21_b1, nullptr, flg, t2a, 64, 64, 128, 1);
    wpk(b21_w2, wslot, 128, 128);
    conv3x3_cl<2><<<cg(64, 64, 128, 2), TB, 0, stream>>>(
        nullptr, 0, 0, t2a, 128, wslot, b21_b2, nullptr, flg, x2_1, 64, 64, 128, 1);

    // ---- caun2: ctx = pool(x1_0) -> [2,64,64,64] cl
    pool2_cl<<<blocks(524288), TB, 0, stream>>>(x1_0, flg, ctx2, 2, 64, 64, 64);
    wpk(c2_w1, wslot, 64, 64);
    conv3x3_cl<2><<<cg(64, 64, 64, 2), TB, 0, stream>>>(
        nullptr, 0, 0, ctx2, 64, wslot, c2_b1, c2_a1, flg, f2a, 64, 64, 64, 2);
    wpk(c2_w2, wslot, 32, 64);
    conv3x3_cl<1><<<cg(64, 64, 32, 1), TB, 0, stream>>>(
        nullptr, 0, 0, f2a, 64, wslot, c2_b2, c2_a2, flg, f2b, 64, 64, 32, 2);
    b2bpack<<<blocks(128 * 36 * 32), TB, 0, stream>>>(c2_kw, flg, wslot, 128 * 36 * 32);
    caun_v3<<<dim3(64, 2, 2), TB, 0, stream>>>(
        f2b, x2_1, 0, wslot, c2_kb, flg, x2up, 128, 32, 64, 64);

    // ---- block12: cat(x1_0 -> cl [64], x2up cl[128]) -> 64 -> 64 @128x128
    nchw2cl<<<2 * 2 * 256, TB, 0, stream>>>(x1_0, flg, x1cl, 64, 16384);
    wpk(b12_w1, wslot, 64, 192);
    conv3x3_cl<4><<<cg(128, 128, 64, 4), TB, 0, stream>>>(
        x1cl, 64, 0, x2up, 128, wslot, b12_b1, nullptr, flg, t1a, 128, 128, 64, 1);
    wpk(b12_w2, wslot, 64, 64);
    conv3x3_cl<4><<<cg(128, 128, 64, 4), TB, 0, stream>>>(
        nullptr, 0, 0, t1a, 64, wslot, b12_b2, nullptr, flg, x1_2, 128, 128, 64, 1);

    // ---- caun1: ctx = pool(x0_0) -> [2,128,128,32] cl
    pool2_cl<<<blocks(1048576), TB, 0, stream>>>(x0_0, flg, ctx1, 2, 32, 128, 128);
    wpk(c1_w1, wslot, 32, 32);
    conv3x3_cl<2><<<cg(128, 128, 32, 2), TB, 0, stream>>>(
        nullptr, 0, 0, ctx1, 32, wslot, c1_b1, c1_a1, flg, f1a, 128, 128, 32, 2);
    wpk(c1_w2, wslot, 16, 32);
    conv3x3_cl<2><<<cg(128, 128, 16, 2), TB, 0, stream>>>(
        nullptr, 0, 0, f1a, 32, wslot, c1_b2, c1_a2, flg, f1b, 128, 128, 16, 2);
    b2bpack<<<blocks(64 * 36 * 16), TB, 0, stream>>>(c1_kw, flg, kw1p, 64 * 36 * 16);
    caun_v3<<<dim3(256, 2, 1), TB, 0, stream>>>(
        f1b, x1_2, 0, kw1p, c1_kb, flg, x1up, 64, 16, 128, 128);

    // ---- block03: cat(x0_0 [32], x1up cl[64]) -> 32 -> 32 @256x256
    wpk(b03_w1, wtail, 32, 96);
    if (have_x0cl) {
        conv3x3_cl<4><<<cg(256, 256, 32, 4), TB, 0, stream>>>(
            x0cl, 32, 0, x1up, 64, wtail, b03_b1, nullptr, flg, t0a, 256, 256, 32, 1);
    } else {
        conv3x3_cl<4><<<cg(256, 256, 32, 4), TB, 0, stream>>>(
            x0_0, 32, 1, x1up, 64, wtail, b03_b1, nullptr, flg, t0a, 256, 256, 32, 1);
    }
    wpk(b03_w2, wtail, 32, 32);
    conv3x3_cl<4><<<cg(256, 256, 32, 4), TB, 0, stream>>>(
        nullptr, 0, 0, t0a, 32, wtail, b03_b2, nullptr, flg, x0_3, 256, 256, 32, 1);

    // ---- memory-bank residual fusion (in place, cl) + final 1x1 conv -> [2,2,256,256]
    memnorm_kernel<<<1, 64, 0, stream>>>(memw, flg, mn);
    memfuse_kernel<<<512, TB, 0, stream>>>(x0_3, mn);
    final1x1_kernel<<<512, TB, 0, stream>>>(x0_3, fin_w, fin_b, flg, d_out, 256 * 256);
}

// Round 14
// 650.353 us; speedup vs baseline: 1.1854x; 1.1854x over previous
//
#include <hip/hip_runtime.h>
#include <hip/hip_bf16.h>
#include <math.h>

typedef __hip_bfloat16 bf16;
typedef short short8 __attribute__((ext_vector_type(8)));   // bf16x8 MFMA frag (4 VGPRs)
typedef float f32x4 __attribute__((ext_vector_type(4)));    // MFMA accumulator

static __device__ __forceinline__ float b2f(bf16 x) { return __bfloat162float(x); }
static __device__ __forceinline__ bf16  f2b(float x) { return __float2bfloat16(x); }
static __device__ __forceinline__ short f2bs(float x) { bf16 t = f2b(x); return *reinterpret_cast<short*>(&t); }

// Polymorphic input load: isb=true -> bf16 storage, else f32 storage.
static __device__ __forceinline__ float ldin(const void* p, size_t i, bool isb) {
    return isb ? b2f(((const bf16*)p)[i]) : ((const float*)p)[i];
}

// ---------------------------------------------------------------- dtype detect
__global__ void detect_kernel(const unsigned int* __restrict__ x, float* __restrict__ flagp) {
    __shared__ int sh[64];
    int insane = 0;
    for (int i = threadIdx.x; i < 1024; i += 64) {
        unsigned int lo = (x[i] & 0xFFFFu) << 16;
        float v = __uint_as_float(lo);
        if (!(fabsf(v) <= 1e6f)) insane++;
    }
    sh[threadIdx.x] = insane;
    __syncthreads();
    if (threadIdx.x == 0) {
        int t = 0;
        for (int i = 0; i < 64; ++i) t += sh[i];
        *flagp = (t < 16) ? 1.f : 0.f;            // 1 => inputs are bf16
    }
}

// ---------------------------------------------------------------- diagnostic fill
__global__ void diag_fill(unsigned int* __restrict__ out, int nwords, float val) {
    int i = blockIdx.x * blockDim.x + threadIdx.x;
    if (i < nwords) {
        unsigned short h = (unsigned short)(__float_as_uint(val) >> 16);
        out[i] = ((unsigned int)h << 16) | h;
    }
}

// ---------------------------------------------------------------- weight pack: [co][ci][tap] -> [tap][co][ci] bf16
__global__ void wpack_kernel(const void* __restrict__ wt, const float* __restrict__ flg,
                             bf16* __restrict__ dst, int Cout, int Cin) {
    bool isb = (*flg != 0.f);
    int n = Cout * Cin * 9;
    int idx = blockIdx.x * blockDim.x + threadIdx.x;
    if (idx >= n) return;
    int ci = idx % Cin;
    int co = (idx / Cin) % Cout;
    int tap = idx / (Cin * Cout);
    dst[idx] = f2b(ldin(wt, ((size_t)co * Cin + ci) * 9 + tap, isb));
}

// ---------------------------------------------------------------- flat convert to bf16 (caun kw pack)
__global__ void b2bpack(const void* __restrict__ src, const float* __restrict__ flg,
                        bf16* __restrict__ dst, int n) {
    bool isb = (*flg != 0.f);
    int i = blockIdx.x * blockDim.x + threadIdx.x;
    if (i < n) dst[i] = f2b(ldin(src, i, isb));
}

// ---------------------------------------------------------------- NCHW ext -> channels-last bf16 (LDS tile transpose)
__global__ void nchw2cl(const void* __restrict__ in, const float* __restrict__ flg,
                        bf16* __restrict__ out, int C, int HW) {
    __shared__ bf16 t[32][72];
    bool isb = (*flg != 0.f);
    int npx = HW >> 6, nc = C >> 5;
    int blk = blockIdx.x;
    int px0 = (blk % npx) << 6;
    int c0  = ((blk / npx) % nc) << 5;
    int b   = blk / (npx * nc);
    for (int i = threadIdx.x; i < 2048; i += 256) {
        int px = i & 63, c = i >> 6;
        t[c][px] = f2b(ldin(in, ((size_t)(b * C + c0 + c)) * HW + px0 + px, isb));
    }
    __syncthreads();
    for (int i = threadIdx.x; i < 2048; i += 256) {
        int c = i & 31, px = i >> 5;
        out[((size_t)b * HW + px0 + px) * C + c0 + c] = t[c][px];
    }
}

// ---------------------------------------------------------------- 2x2 mean pool: NCHW ext -> channels-last bf16 ws
__global__ void pool2_cl(const void* __restrict__ in, const float* __restrict__ flg,
                         bf16* __restrict__ out, int B, int C, int H2, int W2) {
    bool isb = (*flg != 0.f);
    int idx = blockIdx.x * blockDim.x + threadIdx.x;
    int total = B * H2 * W2 * C;
    if (idx >= total) return;
    int c = idx % C;
    int pix = idx / C;
    int w = pix % W2;
    int h = (pix / W2) % H2;
    int b = pix / (W2 * H2);
    int H = H2 * 2, W = W2 * 2;
    size_t base = ((size_t)(b * C + c)) * H * W;
    float s = ldin(in, base + (size_t)(2*h)*W + 2*w, isb)   + ldin(in, base + (size_t)(2*h)*W + 2*w + 1, isb)
            + ldin(in, base + (size_t)(2*h+1)*W + 2*w, isb) + ldin(in, base + (size_t)(2*h+1)*W + 2*w + 1, isb);
    out[idx] = f2b(0.25f * s);
}

// ---------------------------------------------------------------- MFMA conv3x3, channels-last, no LDS (kw-outer)
template<int RT>
__global__ __launch_bounds__(256) void conv3x3_cl(
        const void* __restrict__ in1, int C1, int ext1,
        const bf16* __restrict__ in2, int C2,
        const bf16* __restrict__ wp,
        const void* __restrict__ bias,
        const void* __restrict__ alpha,
        const float* __restrict__ flg,
        bf16* __restrict__ out,
        int H, int W, int Cout, int act) {
    const bool isb = (*flg != 0.f);
    const int Cin = C1 + C2;
    const int lane = threadIdx.x & 63;
    const int wave = threadIdx.x >> 6;
    const int quad = lane >> 4, l16 = lane & 15;
    const int cot = Cout >> 4;
    const int b = blockIdx.z / cot;
    const int co_base = (blockIdx.z % cot) << 4;
    const int r0 = (blockIdx.y * 4 + wave) * RT;
    const int c0 = blockIdx.x << 4;
    const int cog = co_base + l16;

    float bv = ldin(bias, cog, isb);
    f32x4 acc[RT];
    #pragma unroll
    for (int t = 0; t < RT; ++t) acc[t] = {bv, bv, bv, bv};

    for (int ci0 = 0; ci0 < Cin; ci0 += 32) {
        const bool from1 = (ci0 < C1);
        #pragma unroll
        for (int kw = 0; kw < 3; ++kw) {
            const int iw = c0 + l16 + kw - 1;
            const bool okc = (iw >= 0) && (iw < W);
            short8 F[RT + 2];
            #pragma unroll
            for (int j = 0; j < RT + 2; ++j) {
                const int ih = r0 + j - 1;
                const bool ok = okc && (ih >= 0) && (ih < H);
                F[j] = short8{0, 0, 0, 0, 0, 0, 0, 0};
                if (from1) {
                    if (ext1) {
                        if (ok) {
                            size_t base = ((size_t)(b * C1 + ci0 + quad * 8)) * H * W
                                        + (size_t)ih * W + iw;
                            #pragma unroll
                            for (int jj = 0; jj < 8; ++jj)
                                F[j][jj] = f2bs(ldin(in1, base + (size_t)jj * H * W, isb));
                        }
                    } else {
                        if (ok)
                            F[j] = *(const short8*)&((const bf16*)in1)[
                                (((size_t)(b * H) + ih) * W + iw) * C1 + ci0 + quad * 8];
                    }
                } else {
                    if (ok)
                        F[j] = *(const short8*)&in2[(((size_t)(b * H) + ih) * W + iw) * C2
                                                     + (ci0 - C1) + quad * 8];
                }
            }
            #pragma unroll
            for (int kh = 0; kh < 3; ++kh) {
                short8 bfrag = *(const short8*)&wp[((size_t)(kh * 3 + kw) * Cout + cog) * Cin
                                                   + ci0 + quad * 8];
                #pragma unroll
                for (int t = 0; t < RT; ++t)
                    acc[t] = __builtin_amdgcn_mfma_f32_16x16x32_bf16(F[t + kh], bfrag, acc[t], 0, 0, 0);
            }
        }
    }

    float a = (act == 2) ? ldin(alpha, cog, isb) : 0.f;
    #pragma unroll
    for (int t = 0; t < RT; ++t) {
        #pragma unroll
        for (int reg = 0; reg < 4; ++reg) {
            float v = acc[t][reg];
            if (act == 1) v = fmaxf(v, 0.f);
            else if (act == 2) v = (v >= 0.f) ? v : a * v;
            out[(((size_t)(b * H) + r0 + t) * W + c0 + (quad << 2) + reg) * Cout + cog] = f2b(v);
        }
    }
}

// ---------------------------------------------------------------- CAUN v3: block = (8x8 input tile, b, CC-ch chunk)
// CC=16: LDS ~27.5 KB -> 5 blocks/CU, grid x4 vs CC=64 (fixes round-13's 5.4%
// occupancy: 128-block grids + 69 KB LDS + serial 64-c loop with no resident
// waves to hide per-iteration LDS round-trip latency).
template<int CC>
__global__ __launch_bounds__(256) void caun_v3(
        const bf16* __restrict__ f,
        const void* __restrict__ xlow, int xext,
        const bf16* __restrict__ kwp,
        const void* __restrict__ kb,
        const float* __restrict__ flg,
        bf16* __restrict__ out,
        int C, int K, int H, int W) {
    __shared__ float lg_s[4][48 * 17];          // per-wave D transpose
    __shared__ float kb_s[36 * (CC + 2)];       // bias, [j][c] padded
    __shared__ bf16  neigh_s[100 * (CC + 2)];   // 10x10 halo x CC, [cell][c] padded
    __shared__ bf16  out_s[CC * 258];           // [c][16x16 px] padded

    const bool isb = (*flg != 0.f);
    const int tw = W >> 3;
    const int h0 = (blockIdx.x / tw) << 3;
    const int w0 = (blockIdx.x % tw) << 3;
    const int b  = blockIdx.y;
    const int c0 = blockIdx.z * CC;
    const int tid = threadIdx.x, wave = tid >> 6, lane = tid & 63;
    const int quad = lane >> 4, l16 = lane & 15;

    // ---- stage clamped neighbor halo (c-contiguous loads)
    for (int i = tid; i < 100 * CC; i += 256) {
        int c = i % CC, cell = i / CC;
        int r = cell / 10, q = cell % 10;
        int ih = min(max(h0 + r - 1, 0), H - 1);
        int iw = min(max(w0 + q - 1, 0), W - 1);
        float v = xext
            ? ldin(xlow, ((size_t)(b * C + c0 + c)) * H * W + (size_t)ih * W + iw, isb)
            : b2f(((const bf16*)xlow)[(((size_t)(b * H) + ih) * W + iw) * C + c0 + c]);
        neigh_s[cell * (CC + 2) + c] = f2b(v);
    }
    // ---- stage bias chunk
    for (int i = tid; i < 36 * CC; i += 256) {
        int c = i % CC, j = i / CC;
        kb_s[j * (CC + 2) + c] = ldin(kb, (size_t)(c0 + c) * 36 + j, isb);
    }

    // ---- hoist B-frags (f) for this wave's 16 px (2 input rows x 8 cols)
    const int hl = (wave << 1) + (l16 >> 3);
    const int wl = l16 & 7;
    const size_t fpx = ((size_t)b * H * W + (size_t)(h0 + hl) * W + (w0 + wl)) * K;
    const int nkc = ((K + 31) & ~31) >> 5;          // 1 or 2
    const short8 z8 = {0, 0, 0, 0, 0, 0, 0, 0};
    short8 Bf[2];
    {
        int kq0 = quad * 8;
        Bf[0] = (kq0 < K) ? *(const short8*)&f[fpx + kq0] : z8;
        Bf[1] = (nkc > 1) ? *(const short8*)&f[fpx + 32 + quad * 8] : z8;
    }
    __syncthreads();

    // epilogue lane mapping: px16 = lane>>2 (== MFMA l16/D-col), g = lane&3
    const int epx = lane >> 2, eg = lane & 3;
    const int hl_e = (wave << 1) + (epx >> 3);
    const int wl_e = epx & 7;
    float* ls = &lg_s[wave][0];

    for (int c = 0; c < CC; ++c) {
        const size_t crow = (size_t)(c0 + c) * 36;
        f32x4 a0 = {0,0,0,0}, a1 = {0,0,0,0}, a2 = {0,0,0,0};
        #pragma unroll
        for (int ch = 0; ch < 2; ++ch) {
            if (ch >= nkc) break;
            int kq = ch * 32 + quad * 8;
            bool kok = kq < K;
            short8 f0 = kok ? *(const short8*)&kwp[(crow + l16) * K + kq] : z8;
            short8 f1 = kok ? *(const short8*)&kwp[(crow + 16 + l16) * K + kq] : z8;
            short8 f2 = (kok && l16 < 4) ? *(const short8*)&kwp[(crow + 32 + l16) * K + kq] : z8;
            a0 = __builtin_amdgcn_mfma_f32_16x16x32_bf16(f0, Bf[ch], a0, 0, 0, 0);
            a1 = __builtin_amdgcn_mfma_f32_16x16x32_bf16(f1, Bf[ch], a1, 0, 0, 0);
            a2 = __builtin_amdgcn_mfma_f32_16x16x32_bf16(f2, Bf[ch], a2, 0, 0, 0);
        }
        // wave-private transpose (no barrier needed)
        #pragma unroll
        for (int reg = 0; reg < 4; ++reg) {
            int jr = (quad << 2) + reg;
            ls[jr * 17 + l16]        = a0[reg];
            ls[(16 + jr) * 17 + l16] = a1[reg];
            ls[(32 + jr) * 17 + l16] = a2[reg];
        }
        // epilogue: lane = (px16, g)
        float lg[9], nv[9];
        #pragma unroll
        for (int n = 0; n < 9; ++n) {
            int j = n * 4 + eg;
            lg[n] = ls[j * 17 + epx] + kb_s[j * (CC + 2) + c];
            int cell = (hl_e + n / 3) * 10 + (wl_e + n % 3);
            nv[n] = b2f(neigh_s[cell * (CC + 2) + c]);
        }
        float mx = -1e30f;
        #pragma unroll
        for (int n = 0; n < 9; ++n) mx = fmaxf(mx, lg[n]);
        float se = 0.f, accv = 0.f;
        #pragma unroll
        for (int n = 0; n < 9; ++n) {
            float e = expf(lg[n] - mx);
            se += e;
            accv = fmaf(e, nv[n], accv);
        }
        int row_l = (wl_e << 1) + (eg & 1);     // 2w+v
        int col_l = (hl_e << 1) + (eg >> 1);    // 2h+u
        out_s[c * 258 + (row_l << 4) + col_l] = f2b(accv / se);
    }

    __syncthreads();
    // ---- coalesced write-out: consecutive lanes -> consecutive c
    const size_t obase = (size_t)b * 4 * H * W;
    for (int i = tid; i < 256 * CC; i += 256) {
        int c = i % CC, pxl = i / CC;
        int row_l = pxl >> 4, col_l = pxl & 15;
        size_t P = obase + (size_t)(2 * w0 + row_l) * (2 * W) + (2 * h0 + col_l);
        out[P * C + c0 + c] = out_s[c * 258 + pxl];
    }
}

// ---------------------------------------------------------------- memory bank: row-l2norm of mem
__global__ void memnorm_kernel(const void* __restrict__ mem, const float* __restrict__ flg,
                               float* __restrict__ mn) {
    bool isb = (*flg != 0.f);
    int s = threadIdx.x;
    float v[32];
    float ss = 0.f;
    #pragma unroll
    for (int c = 0; c < 32; ++c) { v[c] = ldin(mem, s * 32 + c, isb); ss += v[c] * v[c]; }
    float inv = 1.f / fmaxf(sqrtf(ss), 1e-12f);
    #pragma unroll
    for (int c = 0; c < 32; ++c) mn[s * 32 + c] = v[c] * inv;
}

// ---------------------------------------------------------------- memory fusion (in place, channels-last bf16 ws)
__global__ __launch_bounds__(256, 2) void memfuse_kernel(
        bf16* __restrict__ x, const float* __restrict__ mn) {
    __shared__ float mns[64 * 32];
    for (int i = threadIdx.x; i < 64 * 32; i += blockDim.x) mns[i] = mn[i];
    __syncthreads();
    int idx = blockIdx.x * blockDim.x + threadIdx.x;
    bf16* xp = x + (size_t)idx * 32;

    float feat[32];
    float ss = 0.f;
    #pragma unroll
    for (int c = 0; c < 32; ++c) { feat[c] = b2f(xp[c]); ss += feat[c] * feat[c]; }
    float inv = 1.f / fmaxf(sqrtf(ss), 1e-12f);

    float se = 0.f;
    float racc[32];
    #pragma unroll
    for (int c = 0; c < 32; ++c) racc[c] = 0.f;

    for (int s = 0; s < 64; ++s) {
        const float* mr = mns + s * 32;
        float dot = 0.f;
        #pragma unroll
        for (int c = 0; c < 32; ++c) dot = fmaf(feat[c], mr[c], dot);
        float e = expf(dot * inv);
        se += e;
        #pragma unroll
        for (int c = 0; c < 32; ++c) racc[c] = fmaf(e, mr[c], racc[c]);
    }
    float rse = 1.f / se;
    #pragma unroll
    for (int c = 0; c < 32; ++c)
        xp[c] = f2b(feat[c] + racc[c] * rse);
}

// ---------------------------------------------------------------- final 1x1 conv 32 -> 2 (x channels-last)
__global__ void final1x1_kernel(const bf16* __restrict__ x,
                                const void* __restrict__ fw, const void* __restrict__ fb,
                                const float* __restrict__ flg,
                                void* __restrict__ out, int HW) {
    bool isb = (*flg != 0.f);
    int idx = blockIdx.x * blockDim.x + threadIdx.x;
    int b = idx / HW, p = idx % HW;
    const bf16* xp = x + (size_t)idx * 32;
    float a0 = ldin(fb, 0, isb), a1 = ldin(fb, 1, isb);
    #pragma unroll
    for (int c = 0; c < 32; ++c) {
        float v = b2f(xp[c]);
        a0 = fmaf(v, ldin(fw, c, isb), a0);
        a1 = fmaf(v, ldin(fw, 32 + c, isb), a1);
    }
    size_t i0 = (size_t)b * 2 * HW + p;
    size_t i1 = i0 + HW;
    if (isb) { ((bf16*)out)[i0] = f2b(a0); ((bf16*)out)[i1] = f2b(a1); }
    else     { ((float*)out)[i0] = a0;     ((float*)out)[i1] = a1; }
}

// ================================================================ host
extern "C" void kernel_launch(void* const* d_in, const int* in_sizes, int n_in,
                              void* d_out, int out_size, void* d_ws, size_t ws_size,
                              hipStream_t stream) {
    const void* x0_0 = d_in[0];
    const void* x1_0 = d_in[1];
    const void* x2_0 = d_in[2];
    const void* x3_0 = d_in[3];
    const void* c3_w1 = d_in[4];  const void* c3_b1 = d_in[5];  const void* c3_a1 = d_in[6];
    const void* c3_w2 = d_in[7];  const void* c3_b2 = d_in[8];  const void* c3_a2 = d_in[9];
    const void* c3_kw = d_in[10]; const void* c3_kb = d_in[11];
    const void* c2_w1 = d_in[12]; const void* c2_b1 = d_in[13]; const void* c2_a1 = d_in[14];
    const void* c2_w2 = d_in[15]; const void* c2_b2 = d_in[16]; const void* c2_a2 = d_in[17];
    const void* c2_kw = d_in[18]; const void* c2_kb = d_in[19];
    const void* c1_w1 = d_in[20]; const void* c1_b1 = d_in[21]; const void* c1_a1 = d_in[22];
    const void* c1_w2 = d_in[23]; const void* c1_b2 = d_in[24]; const void* c1_a2 = d_in[25];
    const void* c1_kw = d_in[26]; const void* c1_kb = d_in[27];
    const void* b21_w1 = d_in[28]; const void* b21_b1 = d_in[29];
    const void* b21_w2 = d_in[30]; const void* b21_b2 = d_in[31];
    const void* b12_w1 = d_in[32]; const void* b12_b1 = d_in[33];
    const void* b12_w2 = d_in[34]; const void* b12_b2 = d_in[35];
    const void* b03_w1 = d_in[36]; const void* b03_b1 = d_in[37];
    const void* b03_w2 = d_in[38]; const void* b03_b2 = d_in[39];
    const void* fin_w = d_in[40];  const void* fin_b = d_in[41];
    const void* memw  = d_in[42];
    (void)in_sizes; (void)n_in;

    const int TB = 256;
    auto blocks = [](int n) { return (n + 255) / 256; };

    const size_t NEED = 25165824 + 65536;
    if (ws_size < NEED) {
        diag_fill<<<blocks(out_size / 2), TB, 0, stream>>>(
            (unsigned int*)d_out, out_size / 2, (float)ws_size);
        return;
    }
    const size_t NEED_X0 = 25165824 + 8388608 + 65536 + 256;
    const bool have_x0cl = (ws_size >= NEED_X0);

    size_t tail = (ws_size - 65536) & ~(size_t)255;
    bf16*  wtail = (bf16*)((char*)d_ws + tail);
    float* mn    = (float*)((char*)d_ws + tail + 55296);
    float* flg   = (float*)((char*)d_ws + tail + 63488);

    // 24 MiB arena (12,582,912 bf16 elems), channels-last, verified live ranges.
    bf16* A = (bf16*)d_ws;
    bf16* x3up  = A + 0;         // [2,64,64,256]
    bf16* ctx3p = A + 2097152;   // [2,32,32,128]
    bf16* f3a   = A + 2359296;   // [2,32,32,128]
    bf16* f3b   = A + 2621440;   // [2,32,32,64]
    bf16* kw3p  = A + 3000000;   // 589,824 elems (free during caun3)
    bf16* t2a   = A + 2097152;   // [2,64,64,128]
    bf16* x2cl  = A + 3145728;   // [2,64,64,128]
    bf16* x2_1  = A + 0;         // [2,64,64,128]
    bf16* ctx2  = A + 1048576;   // [2,64,64,64]
    bf16* f2a   = A + 1572864;   // [2,64,64,64]
    bf16* f2b   = A + 2097152;   // [2,64,64,32]
    bf16* x2up  = A + 2359296;   // [2,128,128,128]
    bf16* t1a   = A + 0;         // [2,128,128,64]
    bf16* x1cl  = A + 6995968;   // [2,128,128,64]
    bf16* x1_2  = A + 10485760;  // [2,128,128,64]
    bf16* ctx1  = A + 4194304;   // [2,128,128,32]
    bf16* f1a   = A + 5242880;   // [2,128,128,32]
    bf16* f1b   = A + 9437184;   // [2,128,128,16]
    bf16* kw1p  = A + 8388608;   // 36,864 elems (free gap during caun1)
    bf16* x1up  = A + 0;         // [2,256,256,64]
    bf16* t0a   = A + 8388608;   // [2,256,256,32]
    bf16* x0_3  = A + 0;         // [2,256,256,32]
    bf16* wslot = A + 6553600;   // conv weight packs + caun2 kw pack
    bf16* x0cl  = A + 12582912;  // [2,256,256,32] (only if have_x0cl)

    detect_kernel<<<1, 64, 0, stream>>>((const unsigned int*)x0_0, flg);

    auto wpk = [&](const void* w, bf16* dst, int Cout, int Cin) {
        wpack_kernel<<<blocks(Cout * Cin * 9), TB, 0, stream>>>(w, flg, dst, Cout, Cin);
    };
    auto cg = [](int H, int W, int Cout, int RT) {
        return dim3(W >> 4, H / (4 * RT), 2 * (Cout >> 4));
    };

    if (have_x0cl)
        nchw2cl<<<2 * 1 * 1024, TB, 0, stream>>>(x0_0, flg, x0cl, 32, 65536);

    // ---- caun3: ctx = pool(x2_0) -> [2,32,32,128] cl
    pool2_cl<<<blocks(262144), TB, 0, stream>>>(x2_0, flg, ctx3p, 2, 128, 32, 32);
    wpk(c3_w1, wslot, 128, 128);
    conv3x3_cl<1><<<cg(32, 32, 128, 1), TB, 0, stream>>>(
        nullptr, 0, 0, ctx3p, 128, wslot, c3_b1, c3_a1, flg, f3a, 32, 32, 128, 2);
    wpk(c3_w2, wslot, 64, 128);
    conv3x3_cl<1><<<cg(32, 32, 64, 1), TB, 0, stream>>>(
        nullptr, 0, 0, f3a, 128, wslot, c3_b2, c3_a2, flg, f3b, 32, 32, 64, 2);
    b2bpack<<<blocks(256 * 36 * 64), TB, 0, stream>>>(c3_kw, flg, kw3p, 256 * 36 * 64);
    caun_v3<16><<<dim3(16, 2, 16), TB, 0, stream>>>(
        f3b, x3_0, 1, kw3p, c3_kb, flg, x3up, 256, 64, 32, 32);

    // ---- block21: cat(x2_0 -> cl [128], x3up cl[256]) -> 128 -> 128 @64x64
    nchw2cl<<<2 * 4 * 64, TB, 0, stream>>>(x2_0, flg, x2cl, 128, 4096);
    wpk(b21_w1, wslot, 128, 384);
    conv3x3_cl<2><<<cg(64, 64, 128, 2), TB, 0, stream>>>(
        x2cl, 128, 0, x3up, 256, wslot, b21_b1, nullptr, flg, t2a, 64, 64, 128, 1);
    wpk(b21_w2, wslot, 128, 128);
    conv3x3_cl<2><<<cg(64, 64, 128, 2), TB, 0, stream>>>(
        nullptr, 0, 0, t2a, 128, wslot, b21_b2, nullptr, flg, x2_1, 64, 64, 128, 1);

    // ---- caun2: ctx = pool(x1_0) -> [2,64,64,64] cl
    pool2_cl<<<blocks(524288), TB, 0, stream>>>(x1_0, flg, ctx2, 2, 64, 64, 64);
    wpk(c2_w1, wslot, 64, 64);
    conv3x3_cl<2><<<cg(64, 64, 64, 2), TB, 0, stream>>>(
        nullptr, 0, 0, ctx2, 64, wslot, c2_b1, c2_a1, flg, f2a, 64, 64, 64, 2);
    wpk(c2_w2, wslot, 32, 64);
    conv3x3_cl<1><<<cg(64, 64, 32, 1), TB, 0, stream>>>(
        nullptr, 0, 0, f2a, 64, wslot, c2_b2, c2_a2, flg, f2b, 64, 64, 32, 2);
    b2bpack<<<blocks(128 * 36 * 32), TB, 0, stream>>>(c2_kw, flg, wslot, 128 * 36 * 32);
    caun_v3<16><<<dim3(64, 2, 8), TB, 0, stream>>>(
        f2b, x2_1, 0, wslot, c2_kb, flg, x2up, 128, 32, 64, 64);

    // ---- block12: cat(x1_0 -> cl [64], x2up cl[128]) -> 64 -> 64 @128x128
    nchw2cl<<<2 * 2 * 256, TB, 0, stream>>>(x1_0, flg, x1cl, 64, 16384);
    wpk(b12_w1, wslot, 64, 192);
    conv3x3_cl<4><<<cg(128, 128, 64, 4), TB, 0, stream>>>(
        x1cl, 64, 0, x2up, 128, wslot, b12_b1, nullptr, flg, t1a, 128, 128, 64, 1);
    wpk(b12_w2, wslot, 64, 64);
    conv3x3_cl<4><<<cg(128, 128, 64, 4), TB, 0, stream>>>(
        nullptr, 0, 0, t1a, 64, wslot, b12_b2, nullptr, flg, x1_2, 128, 128, 64, 1);

    // ---- caun1: ctx = pool(x0_0) -> [2,128,128,32] cl
    pool2_cl<<<blocks(1048576), TB, 0, stream>>>(x0_0, flg, ctx1, 2, 32, 128, 128);
    wpk(c1_w1, wslot, 32, 32);
    conv3x3_cl<2><<<cg(128, 128, 32, 2), TB, 0, stream>>>(
        nullptr, 0, 0, ctx1, 32, wslot, c1_b1, c1_a1, flg, f1a, 128, 128, 32, 2);
    wpk(c1_w2, wslot, 16, 32);
    conv3x3_cl<2><<<cg(128, 128, 16, 2), TB, 0, stream>>>(
        nullptr, 0, 0, f1a, 32, wslot, c1_b2, c1_a2, flg, f1b, 128, 128, 16, 2);
    b2bpack<<<blocks(64 * 36 * 16), TB, 0, stream>>>(c1_kw, flg, kw1p, 64 * 36 * 16);
    caun_v3<16><<<dim3(256, 2, 4), TB, 0, stream>>>(
        f1b, x1_2, 0, kw1p, c1_kb, flg, x1up, 64, 16, 128, 128);

    // ---- block03: cat(x0_0 [32], x1up cl[64]) -> 32 -> 32 @256x256
    wpk(b03_w1, wtail, 32, 96);
    if (have_x0cl) {
        conv3x3_cl<4><<<cg(256, 256, 32, 4), TB, 0, stream>>>(
            x0cl, 32, 0, x1up, 64, wtail, b03_b1, nullptr, flg, t0a, 256, 256, 32, 1);
    } else {
        conv3x3_cl<4><<<cg(256, 256, 32, 4), TB, 0, stream>>>(
            x0_0, 32, 1, x1up, 64, wtail, b03_b1, nullptr, flg, t0a, 256, 256, 32, 1);
    }
    wpk(b03_w2, wtail, 32, 32);
    conv3x3_cl<4><<<cg(256, 256, 32, 4), TB, 0, stream>>>(
        nullptr, 0, 0, t0a, 32, wtail, b03_b2, nullptr, flg, x0_3, 256, 256, 32, 1);

    // ---- memory-bank residual fusion (in place, cl) + final 1x1 conv -> [2,2,256,256]
    memnorm_kernel<<<1, 64, 0, stream>>>(memw, flg, mn);
    memfuse_kernel<<<512, TB, 0, stream>>>(x0_3, mn);
    final1x1_kernel<<<512, TB, 0, stream>>>(x0_3, fin_w, fin_b, flg, d_out, 256 * 256);
}